// Round 4
// baseline (217.476 us; speedup 1.0000x reference)
//
#include <hip/hip_runtime.h>

// RotatedGridPool: B=4, C=256, H=200, W=176, N=128, G=7
// Output: (B*N, C, G, G) fp32.
//
// R4: divergent 8B gathers -> coalesced patch staging.
// Max sample span per ROI < 16 cells per dim (6/7 * 11.25*sqrt(2) + 2), so a
// 16-row x 32-col (64B-aligned) LDS patch per (ROI, 16-channel chunk) always
// covers all referenced cells. Load patch with aligned float4 (8/thread),
// then bilinear-interp entirely from LDS. Out-of-map cells are never loaded;
// samples referencing them carry zero weight onto clamped in-patch cells.

constexpr int Bc = 4;
constexpr int Cc = 256;
constexpr int Hc = 200;
constexpr int Wc = 176;
constexpr int Nc = 128;
constexpr int G  = 7;
constexpr int NPTS = G * G;            // 49
constexpr int CSPLIT = 16;             // blocks per ROI
constexpr int CCHUNK = Cc / CSPLIT;    // 16 channels per block
constexpr int PR = 16;                 // patch rows
constexpr int PC = 32;                 // patch cols (64B aligned)
constexpr int ELEMS = CCHUNK * NPTS;   // 784
constexpr int HW = Hc * Wc;
constexpr float MIN_Xf = 0.0f;
constexpr float MIN_Yf = -40.0f;

__global__ __launch_bounds__(256) void rot_grid_pool_kernel(
    const float* __restrict__ feat,       // (B,C,H,W)
    const float* __restrict__ rois,       // (B,N,7)
    const float* __restrict__ voxel_size, // (2,)
    const int*   __restrict__ fms,        // scalar stride
    float* __restrict__ out)              // (B*N, C, G, G)
{
    const int bn    = blockIdx.x;         // 0 .. B*N-1
    const int chunk = blockIdx.y;         // 0 .. CSPLIT-1
    const int b     = bn / Nc;
    const int ch0   = chunk * CCHUNK;

    __shared__ __align__(16) float patch[CCHUNK][PR][PC];  // 32 KB
    __shared__ int4   s_o[NPTS];          // 4 LDS offsets (ly*PC+lx) per point
    __shared__ float4 s_w[NPTS];          // 4 weights (validity folded)
    __shared__ int    s_base[2];          // row0, col0

    const int tid = threadIdx.x;

    if (tid < 64) {  // wave 0: theta, point coords, bbox reduce, meta
        const float* roi = rois + (size_t)bn * 7;
        const float rcx = roi[0], rcy = roi[1];
        const float rdx = roi[3], rdy = roi[4];
        const float ang = roi[6];
        const float stride = (float)fms[0];
        const float vxs = voxel_size[0] * stride;
        const float vys = voxel_size[1] * stride;

        const float x1 = (rcx - rdx * 0.5f - MIN_Xf) / vxs;
        const float x2 = (rcx + rdx * 0.5f - MIN_Xf) / vxs;
        const float y1 = (rcy - rdy * 0.5f - MIN_Yf) / vys;
        const float y2 = (rcy + rdy * 0.5f - MIN_Yf) / vys;

        float sina, cosa;
        __sincosf(ang, &sina, &cosa);

        const float wm1 = (float)(Wc - 1);
        const float hm1 = (float)(Hc - 1);
        const float scale1 = (y2 - y1) / fmaxf(x2 - x1, 0.01f);
        const float scale2 = (x2 - x1) / fmaxf(y2 - y1, 0.01f);
        const float t00 = (x2 - x1) / wm1 * cosa;
        const float t01 = (x2 - x1) / wm1 * (-sina) * scale1;
        const float t02 = (x1 + x2 - wm1) / wm1;
        const float t10 = (y2 - y1) / hm1 * sina * scale2;
        const float t11 = (y2 - y1) / hm1 * cosa;
        const float t12 = (y1 + y2 - hm1) / hm1;

        float ix = 1e30f, iy = 1e30f;     // sentinels for lanes 49..63
        if (tid < NPTS) {
            const int row = tid / G;
            const int col = tid - row * G;
            const float xx = (2.0f * (float)col + 1.0f) / (float)G - 1.0f;
            const float yy = (2.0f * (float)row + 1.0f) / (float)G - 1.0f;
            const float gx = t00 * xx + t01 * yy + t02;
            const float gy = t10 * xx + t11 * yy + t12;
            ix = ((gx + 1.0f) * (float)Wc - 1.0f) * 0.5f;
            iy = ((gy + 1.0f) * (float)Hc - 1.0f) * 0.5f;
        }

        // wave-wide min reduction of (ix, iy)
        float mnx = ix, mny = iy;
        #pragma unroll
        for (int d = 1; d < 64; d <<= 1) {
            mnx = fminf(mnx, __shfl_xor(mnx, d, 64));
            mny = fminf(mny, __shfl_xor(mny, d, 64));
        }
        // 16-float-aligned col origin; clamped so patch is fully in-map
        int col0 = ((int)floorf(mnx)) & ~15;
        col0 = min(max(col0, 0), Wc - PC);
        int row0 = (int)floorf(mny);
        row0 = min(max(row0, 0), Hc - PR);

        if (tid == 0) { s_base[0] = row0; s_base[1] = col0; }

        if (tid < NPTS) {
            const float x0f = floorf(ix);
            const float y0f = floorf(iy);
            const float wx1 = ix - x0f, wx0 = 1.0f - wx1;
            const float wy1 = iy - y0f, wy0 = 1.0f - wy1;

            const bool vx0 = (x0f >= 0.0f) && (x0f <= (float)(Wc - 1));
            const bool vx1 = (x0f + 1.0f >= 0.0f) && (x0f + 1.0f <= (float)(Wc - 1));
            const bool vy0 = (y0f >= 0.0f) && (y0f <= (float)(Hc - 1));
            const bool vy1 = (y0f + 1.0f >= 0.0f) && (y0f + 1.0f <= (float)(Hc - 1));

            const int x0i = (int)x0f;
            const int y0i = (int)y0f;
            const int lx0 = min(max(x0i,     0), Wc - 1) - col0;  // in [0,PC)
            const int lx1 = min(max(x0i + 1, 0), Wc - 1) - col0;
            const int ly0 = min(max(y0i,     0), Hc - 1) - row0;  // in [0,PR)
            const int ly1 = min(max(y0i + 1, 0), Hc - 1) - row0;

            s_o[tid] = make_int4(ly0 * PC + lx0, ly0 * PC + lx1,
                                 ly1 * PC + lx0, ly1 * PC + lx1);
            s_w[tid] = make_float4((vy0 && vx0) ? wy0 * wx0 : 0.0f,
                                   (vy0 && vx1) ? wy0 * wx1 : 0.0f,
                                   (vy1 && vx0) ? wy1 * wx0 : 0.0f,
                                   (vy1 && vx1) ? wy1 * wx1 : 0.0f);
        }
    }
    __syncthreads();

    const int row0 = s_base[0];
    const int col0 = s_base[1];

    // ---- load phase: 16 ch x 16 rows x 32 cols = 32 KB, aligned float4 ----
    const float* __restrict__ fb = feat + ((size_t)b * Cc + ch0) * HW
                                 + (size_t)row0 * Wc + col0;
    #pragma unroll
    for (int i = 0; i < 8; ++i) {
        const int idx = tid + i * 256;        // 0..2047 float4 slots
        const int ch  = idx >> 7;             // 128 slots per channel
        const int rem = idx & 127;
        const int row = rem >> 3;
        const int cg  = (rem & 7) * 4;
        const float4 v = *(const float4*)(fb + (size_t)ch * HW + row * Wc + cg);
        *(float4*)&patch[ch][row][cg] = v;
    }
    __syncthreads();

    // ---- compute phase: 16 ch x 49 pts from LDS, coalesced writes ----
    float* __restrict__ ob = out + ((size_t)bn * Cc + ch0) * NPTS;
    #pragma unroll
    for (int k = 0; k < 4; ++k) {
        const int e = tid + k * 256;
        if (e < ELEMS) {
            const int c  = e / NPTS;
            const int pt = e - c * NPTS;
            const int4   o = s_o[pt];
            const float4 w = s_w[pt];
            const float* pc = &patch[c][0][0];
            ob[e] = w.x * pc[o.x] + w.y * pc[o.y]
                  + w.z * pc[o.z] + w.w * pc[o.w];
        }
    }
}

extern "C" void kernel_launch(void* const* d_in, const int* in_sizes, int n_in,
                              void* d_out, int out_size, void* d_ws, size_t ws_size,
                              hipStream_t stream) {
    const float* feat = (const float*)d_in[0];
    const float* rois = (const float*)d_in[1];
    const float* vox  = (const float*)d_in[2];
    const int*   fms  = (const int*)d_in[3];
    float* out = (float*)d_out;

    rot_grid_pool_kernel<<<dim3(Bc * Nc, CSPLIT), dim3(256), 0, stream>>>(
        feat, rois, vox, fms, out);
}

// Round 5
// 216.944 us; speedup vs baseline: 1.0025x; 1.0025x over previous
//
#include <hip/hip_runtime.h>

// RotatedGridPool: B=4, C=256, H=200, W=176, N=128, G=7
// Output: (B*N, C, G, G) fp32.
//
// R5: patch staging with dynamic row count + higher block residency.
// - Patch = [8 ch][rows<=16][32 cols, 64B-aligned]; only the rows actually
//   spanned by the ROI's 49 bilinear footprints are loaded (avg ~10 of 16).
// - CCHUNK 16->8 => LDS 16KB+meta => 8 blocks/CU, 32 waves/CU, so load
//   phases of some blocks overlap compute phases of others.
// - All loads aligned float4; bilinear entirely from LDS; coalesced writes.

constexpr int Bc = 4;
constexpr int Cc = 256;
constexpr int Hc = 200;
constexpr int Wc = 176;
constexpr int Nc = 128;
constexpr int G  = 7;
constexpr int NPTS = G * G;            // 49
constexpr int CSPLIT = 32;             // blocks per ROI
constexpr int CCHUNK = Cc / CSPLIT;    // 8 channels per block
constexpr int PRMAX = 16;              // max patch rows (bound: <=16 cells)
constexpr int PC = 32;                 // patch cols (64B aligned)
constexpr int ELEMS = CCHUNK * NPTS;   // 392
constexpr int HW = Hc * Wc;
constexpr float MIN_Xf = 0.0f;
constexpr float MIN_Yf = -40.0f;

__global__ __launch_bounds__(256, 8) void rot_grid_pool_kernel(
    const float* __restrict__ feat,       // (B,C,H,W)
    const float* __restrict__ rois,       // (B,N,7)
    const float* __restrict__ voxel_size, // (2,)
    const int*   __restrict__ fms,        // scalar stride
    float* __restrict__ out)              // (B*N, C, G, G)
{
    const int bn    = blockIdx.x;         // 0 .. B*N-1
    const int chunk = blockIdx.y;         // 0 .. CSPLIT-1
    const int b     = bn / Nc;
    const int ch0   = chunk * CCHUNK;

    __shared__ __align__(16) float patch[CCHUNK][PRMAX][PC];  // 16 KB
    __shared__ int4   s_o[NPTS];          // 4 LDS offsets (ly*PC+lx) per point
    __shared__ float4 s_w[NPTS];          // 4 weights (validity folded)
    __shared__ int    s_base[3];          // row0, col0, rows

    const int tid = threadIdx.x;

    if (tid < 64) {  // wave 0: theta, point coords, bbox reduce, meta
        const float* roi = rois + (size_t)bn * 7;
        const float rcx = roi[0], rcy = roi[1];
        const float rdx = roi[3], rdy = roi[4];
        const float ang = roi[6];
        const float stride = (float)fms[0];
        const float vxs = voxel_size[0] * stride;
        const float vys = voxel_size[1] * stride;

        const float x1 = (rcx - rdx * 0.5f - MIN_Xf) / vxs;
        const float x2 = (rcx + rdx * 0.5f - MIN_Xf) / vxs;
        const float y1 = (rcy - rdy * 0.5f - MIN_Yf) / vys;
        const float y2 = (rcy + rdy * 0.5f - MIN_Yf) / vys;

        float sina, cosa;
        __sincosf(ang, &sina, &cosa);

        const float wm1 = (float)(Wc - 1);
        const float hm1 = (float)(Hc - 1);
        const float scale1 = (y2 - y1) / fmaxf(x2 - x1, 0.01f);
        const float scale2 = (x2 - x1) / fmaxf(y2 - y1, 0.01f);
        const float t00 = (x2 - x1) / wm1 * cosa;
        const float t01 = (x2 - x1) / wm1 * (-sina) * scale1;
        const float t02 = (x1 + x2 - wm1) / wm1;
        const float t10 = (y2 - y1) / hm1 * sina * scale2;
        const float t11 = (y2 - y1) / hm1 * cosa;
        const float t12 = (y1 + y2 - hm1) / hm1;

        float ix = 0.0f, iy = 0.0f;
        bool active = (tid < NPTS);
        if (active) {
            const int row = tid / G;
            const int col = tid - row * G;
            const float xx = (2.0f * (float)col + 1.0f) / (float)G - 1.0f;
            const float yy = (2.0f * (float)row + 1.0f) / (float)G - 1.0f;
            const float gx = t00 * xx + t01 * yy + t02;
            const float gy = t10 * xx + t11 * yy + t12;
            ix = ((gx + 1.0f) * (float)Wc - 1.0f) * 0.5f;
            iy = ((gy + 1.0f) * (float)Hc - 1.0f) * 0.5f;
        }

        // wave-wide min/max of iy and min of ix (inactive lanes: sentinels)
        float mnx = active ? ix :  1e30f;
        float mny = active ? iy :  1e30f;
        float mxy = active ? iy : -1e30f;
        #pragma unroll
        for (int d = 1; d < 64; d <<= 1) {
            mnx = fminf(mnx, __shfl_xor(mnx, d, 64));
            mny = fminf(mny, __shfl_xor(mny, d, 64));
            mxy = fmaxf(mxy, __shfl_xor(mxy, d, 64));
        }
        // 16-float (64B) aligned col origin, patch fully in-map
        int col0 = ((int)floorf(mnx)) & ~15;
        col0 = min(max(col0, 0), Wc - PC);
        // dynamic row range: cells floor(mny) .. floor(mxy)+1, clamped
        int row0   = min(max((int)floorf(mny), 0), Hc - 1);
        int rowEnd = min(max((int)floorf(mxy) + 1, 0), Hc - 1);
        int rows   = max(rowEnd - row0 + 1, 1);   // <= 16 by span bound

        if (tid == 0) { s_base[0] = row0; s_base[1] = col0; s_base[2] = rows; }

        if (active) {
            const float x0f = floorf(ix);
            const float y0f = floorf(iy);
            const float wx1 = ix - x0f, wx0 = 1.0f - wx1;
            const float wy1 = iy - y0f, wy0 = 1.0f - wy1;

            const bool vx0 = (x0f >= 0.0f) && (x0f <= (float)(Wc - 1));
            const bool vx1 = (x0f + 1.0f >= 0.0f) && (x0f + 1.0f <= (float)(Wc - 1));
            const bool vy0 = (y0f >= 0.0f) && (y0f <= (float)(Hc - 1));
            const bool vy1 = (y0f + 1.0f >= 0.0f) && (y0f + 1.0f <= (float)(Hc - 1));

            const int x0i = (int)x0f;
            const int y0i = (int)y0f;
            const int lx0 = min(max(x0i,     0), Wc - 1) - col0;  // in [0,PC)
            const int lx1 = min(max(x0i + 1, 0), Wc - 1) - col0;
            const int ly0 = min(max(y0i,     0), Hc - 1) - row0;  // in [0,rows)
            const int ly1 = min(max(y0i + 1, 0), Hc - 1) - row0;

            s_o[tid] = make_int4(ly0 * PC + lx0, ly0 * PC + lx1,
                                 ly1 * PC + lx0, ly1 * PC + lx1);
            s_w[tid] = make_float4((vy0 && vx0) ? wy0 * wx0 : 0.0f,
                                   (vy0 && vx1) ? wy0 * wx1 : 0.0f,
                                   (vy1 && vx0) ? wy1 * wx0 : 0.0f,
                                   (vy1 && vx1) ? wy1 * wx1 : 0.0f);
        }
    }
    __syncthreads();

    const int row0 = s_base[0];
    const int col0 = s_base[1];
    const int rows = s_base[2];

    // ---- load phase: 8 ch x rows x 32 cols, aligned float4 ----
    const float* __restrict__ fb = feat + ((size_t)b * Cc + ch0) * HW
                                 + (size_t)row0 * Wc + col0;
    const int per   = rows * 8;               // float4 slots per channel
    const int total = CCHUNK * per;           // <= 1024
    for (int i = tid; i < total; i += 256) {
        const int ch  = i / per;
        const int rem = i - ch * per;
        const int row = rem >> 3;
        const int cg  = (rem & 7) * 4;
        const float4 v = *(const float4*)(fb + (size_t)ch * HW + row * Wc + cg);
        *(float4*)&patch[ch][row][cg] = v;
    }
    __syncthreads();

    // ---- compute phase: 8 ch x 49 pts from LDS, coalesced writes ----
    float* __restrict__ ob = out + ((size_t)bn * Cc + ch0) * NPTS;
    #pragma unroll
    for (int k = 0; k < 2; ++k) {
        const int e = tid + k * 256;
        if (e < ELEMS) {
            const int c  = e / NPTS;
            const int pt = e - c * NPTS;
            const int4   o = s_o[pt];
            const float4 w = s_w[pt];
            const float* pc = &patch[c][0][0];
            ob[e] = w.x * pc[o.x] + w.y * pc[o.y]
                  + w.z * pc[o.z] + w.w * pc[o.w];
        }
    }
}

extern "C" void kernel_launch(void* const* d_in, const int* in_sizes, int n_in,
                              void* d_out, int out_size, void* d_ws, size_t ws_size,
                              hipStream_t stream) {
    const float* feat = (const float*)d_in[0];
    const float* rois = (const float*)d_in[1];
    const float* vox  = (const float*)d_in[2];
    const int*   fms  = (const int*)d_in[3];
    float* out = (float*)d_out;

    rot_grid_pool_kernel<<<dim3(Bc * Nc, CSPLIT), dim3(256), 0, stream>>>(
        feat, rois, vox, fms, out);
}